// Round 5
// baseline (118.631 us; speedup 1.0000x reference)
//
#include <hip/hip_runtime.h>
#include <math.h>

#define Bsz 8
#define Nsz 1024
#define FIN 128
#define Hh  4
#define FO  64
#define COLS 256   // Hh*FO
#define TN  16
#define TM  32
#define NT  (Nsz/TM)   // 32 m-tiles
#define BN  (Bsz*Nsz)
#define XSTR 136   // ushort stride (128 data + 8 pad)
#define LOG2E  1.44269504088896340f
#define CSHIFT 17.3123404906675611f     // 12*log2(e): exp(s-12) == exp2(s*log2e - CSHIFT)
#define NEG08C (-0.8f * CSHIFT)         // leaky in t-domain: fma(0.2, t, -0.8C)

typedef __attribute__((ext_vector_type(8))) short short8;
typedef __attribute__((ext_vector_type(4))) float f32x4;

static __device__ inline ushort f2bf(float f) {           // RNE float->bf16
    uint u = __float_as_uint(f);
    u += 0x7FFFu + ((u >> 16) & 1u);
    return (ushort)(u >> 16);
}

static __device__ inline float fexp2(float x) {
#if __has_builtin(__builtin_amdgcn_exp2f)
    return __builtin_amdgcn_exp2f(x);
#else
    float r; asm("v_exp_f32 %0, %1" : "=v"(r) : "v"(x));
    return r;
#endif
}

// ---------------- Kernel A: h = x@W via MFMA + adj bitmask pack for the same rows ----
// grid 512 = (b, 16-row tile), 256 thr. Wave w = head w (cols w*64..w*64+63).
// W staged per-block into wLDS as bf16 (coalesced dword loads, cvt_pk).
// The block also ballot-packs adj rows [rowbase, rowbase+16) into the 1-bit mask
// (64 KB coalesced HBM read, overlapped with MFMA/store/es phases via TLP) so
// the latency-critical attn kernel never touches the 32 MB adj stream.
__global__ __launch_bounds__(256) void gat_proj(
    const float* __restrict__ x, const float* __restrict__ W,
    const float* __restrict__ a, const int* __restrict__ adj,
    ushort* __restrict__ h_gB, float* __restrict__ es_g,
    float* __restrict__ ed_g, uint* __restrict__ ab)
{
    __shared__ ushort xs[16 * XSTR];       // 4.25 KB
    __shared__ ushort wLDS[COLS * XSTR];   // 68 KB
    const int j    = threadIdx.x;
    const int w    = j >> 6, lane = j & 63, quad = lane >> 4, n16 = lane & 15;
    const int b    = blockIdx.x >> 6, mt16 = blockIdx.x & 63;
    const long rowbase = (long)b * Nsz + mt16 * 16;

    // stage x tile (16x128) as bf16 into LDS (HBM loads issued first)
    {
        const int r = j >> 4, k0 = (j & 15) * 8;
        const float4* g4 = (const float4*)(x + (rowbase + r) * FIN + k0);
        float4 v0 = g4[0], v1 = g4[1];
        ushort u[8] = { f2bf(v0.x), f2bf(v0.y), f2bf(v0.z), f2bf(v0.w),
                        f2bf(v1.x), f2bf(v1.y), f2bf(v1.z), f2bf(v1.w) };
        *(int4*)(xs + r * XSTR + k0) = *(int4*)u;
    }

    // stage W column j: wLDS[j][k] = bf16(W[k][j]) (coalesced across lanes)
    #pragma unroll
    for (int i8 = 0; i8 < 16; i8++) {
        float wv[8];
        #pragma unroll
        for (int ii = 0; ii < 8; ii++) wv[ii] = W[(i8*8 + ii) * COLS + j];
        uint pk4[4];
        #pragma unroll
        for (int i2 = 0; i2 < 4; i2++)
            asm("v_cvt_pk_bf16_f32 %0, %1, %2" : "=v"(pk4[i2]) : "v"(wv[2*i2]), "v"(wv[2*i2+1]));
        *(int4*)(wLDS + j * XSTR + i8*8) = *(int4*)pk4;
    }
    __syncthreads();

    // B fragments from wLDS (2-way bank aliasing on reads -> free)
    short8 bfr[4][4];
    #pragma unroll
    for (int kk = 0; kk < 4; kk++)
        #pragma unroll
        for (int c4 = 0; c4 < 4; c4++)
            bfr[kk][c4] = *(const short8*)(wLDS + (w*64 + c4*16 + n16) * XSTR + kk*32 + quad*8);

    f32x4 acc[4];
    #pragma unroll
    for (int c4 = 0; c4 < 4; c4++)
        #pragma unroll
        for (int r = 0; r < 4; r++) acc[c4][r] = 0.f;

    #pragma unroll
    for (int kk = 0; kk < 4; kk++) {
        short8 af = *(const short8*)(xs + n16 * XSTR + kk*32 + quad*8);
        #pragma unroll
        for (int c4 = 0; c4 < 4; c4++)
            acc[c4] = __builtin_amdgcn_mfma_f32_16x16x32_bf16(af, bfr[kk][c4], acc[c4], 0, 0, 0);
    }

    // ---- h_gB store: [b][mt=row/32][c][k=row%32] bf16 ----
    const int mtile = mt16 >> 1;
    const int kbase = (mt16 & 1) * 16 + quad * 4;
    #pragma unroll
    for (int c4 = 0; c4 < 4; c4++) {
        uint2 pk;
        pk.x = (uint)f2bf(acc[c4][0]) | ((uint)f2bf(acc[c4][1]) << 16);
        pk.y = (uint)f2bf(acc[c4][2]) | ((uint)f2bf(acc[c4][3]) << 16);
        const int c = w*64 + c4*16 + n16;
        *(uint2*)(h_gB + (((long)(b*32 + mtile) * COLS + c) * 32 + kbase)) = pk;
    }

    // ---- es/ed from fp32 accumulators (log2e-scaled; CSHIFT folded into es) ----
    float aS[4], aD[4];
    #pragma unroll
    for (int c4 = 0; c4 < 4; c4++) {
        aS[c4] = a[w * (2*FO) + c4*16 + n16];
        aD[c4] = a[w * (2*FO) + FO + c4*16 + n16];
    }
    #pragma unroll
    for (int reg = 0; reg < 4; reg++) {
        float ps = 0.f, pd = 0.f;
        #pragma unroll
        for (int c4 = 0; c4 < 4; c4++) {
            ps = fmaf(acc[c4][reg], aS[c4], ps);
            pd = fmaf(acc[c4][reg], aD[c4], pd);
        }
        #pragma unroll
        for (int off = 1; off < 16; off <<= 1) {
            ps += __shfl_xor(ps, off, 64);
            pd += __shfl_xor(pd, off, 64);
        }
        if (n16 == 0) {
            const long row = rowbase + quad*4 + reg;
            es_g[(long)w * BN + row] = ps * LOG2E - CSHIFT;
            ed_g[(long)w * BN + row] = pd * LOG2E;
        }
    }

    // ---- ballot-pack adj rows [rowbase, rowbase+16) -> bitmask (64 KB coalesced) ----
    {
        const int* ap  = adj + rowbase * (long)Nsz;
        uint*      abp = ab  + rowbase * (Nsz / 32);
        #pragma unroll 4
        for (int k = 0; k < 64; k++) {
            const int idx = k * 256 + j;                 // 0..16383, wave-chunks 64-aligned
            const unsigned long long m = __ballot(ap[idx] > 0);
            if (lane == 0)
                *(uint2*)&abp[idx >> 5] = make_uint2((uint)m, (uint)(m >> 32));
        }
    }
}

// ---------------- Kernel B: barrier-free main loop, in-block m-split, bitmask adj ----
// grid (Bsz, Nsz/TN), 512 thr. Group g = j>>8 owns m-tiles [16g, 16g+16).
// Wave (g,w) = head w; lane (n16, quad) computes p for row n16, m in [8q, 8q+8)
// == MFMA A-fragment layout, so p stays in registers; main loop has NO barriers.
// adj bits come pre-packed from gat_proj (2 KB/block, L2-resident).
// Denominator l = P x ones via one extra MFMA (D-row layout).
__global__ __launch_bounds__(512, 4) void gat_attn(
    const uint* __restrict__ ab, const ushort* __restrict__ h_gB,
    const float* __restrict__ es_g, const float* __restrict__ ed_g,
    float* __restrict__ out)
{
    // phase1: edT [0,16K) + abT [16K,18.25K) ; phase2: merge [0,20K) + o_lds [20K,36.25K)
    __shared__ __align__(16) char smem[20*1024 + Hh * TN * 65 * 4];
    float (*edT)[Nsz]      = (float (*)[Nsz])smem;                   // [Hh][1024]
    uint  (*abT)[36]       = (uint (*)[36])(smem + 16*1024);         // [16][36]
    float (*o_lds)[TN][65] = (float (*)[TN][65])(smem + 20*1024);    // [Hh][16][65]

    const int j    = threadIdx.x;
    const int g    = j >> 8;                  // m-group
    const int jg   = j & 255;
    const int w    = jg >> 6, lane = jg & 63, quad = lane >> 4, n16 = lane & 15;
    const int b    = blockIdx.x, n0 = blockIdx.y * TN;   // linear%8==b -> XCD b owns batch b
    const long rowb = (long)b * Nsz + n0;

    // stage edT[w][g*512 .. g*512+512): each (g,w) wave stages the half it consumes
    {
        const float* src = ed_g + (long)w * BN + (long)b * Nsz + g*512 + lane*8;
        float* dst = &edT[w][g*512 + lane*8];
        *(float4*)dst       = *(const float4*)src;
        *(float4*)(dst + 4) = *(const float4*)(src + 4);
    }
    // stage adj bits: 16 rows x 32 uints (2 KB, packed by gat_proj)
    if (j < 128) {
        const int r = j >> 3, c = (j & 7) * 4;
        *(int4*)&abT[r][c] = *(const int4*)(ab + (rowb + r) * 32 + c);
    }
    const float esC = es_g[(long)w * BN + rowb + n16];   // log2e-scaled, -CSHIFT folded
    __syncthreads();                                     // the ONLY pre-epilogue barrier

    f32x4 acc[4], accl;
    #pragma unroll
    for (int c4 = 0; c4 < 4; c4++)
        #pragma unroll
        for (int r = 0; r < 4; r++) acc[c4][r] = 0.f;
    #pragma unroll
    for (int r = 0; r < 4; r++) accl[r] = 0.f;

    short8 ones;
    #pragma unroll
    for (int i = 0; i < 8; i++) ones[i] = (short)0x3F80;    // bf16 1.0

    const ushort* hb = h_gB + (long)b * (Nsz * COLS);
    short8 h0[4], h1[4];

#define PRE_H(t, H) {                                                           \
    const ushort* hp = hb + (long)(t) * (COLS * TM);                            \
    _Pragma("unroll")                                                           \
    for (int c4 = 0; c4 < 4; c4++)                                              \
        H[c4] = *(const short8*)(hp + (w*64 + c4*16 + n16) * TM + quad*8); }

#define SUBT(t, HC, ABU) {                                                      \
    f32x4 ev0 = *(const f32x4*)&edT[w][(t)*32 + quad*8];                        \
    f32x4 ev1 = *(const f32x4*)&edT[w][(t)*32 + quad*8 + 4];                    \
    const uint b8 = ((ABU) >> (quad*8)) & 0xffu;                                \
    uint pk[4];                                                                 \
    _Pragma("unroll")                                                           \
    for (int p2 = 0; p2 < 4; p2++) {                                            \
        float t0 = esC + (p2 < 2 ? ev0[p2*2]     : ev1[(p2-2)*2]);              \
        float t1 = esC + (p2 < 2 ? ev0[p2*2 + 1] : ev1[(p2-2)*2 + 1]);          \
        float u0 = fmaxf(t0, fmaf(0.2f, t0, NEG08C));                           \
        float u1 = fmaxf(t1, fmaf(0.2f, t1, NEG08C));                           \
        float e0 = fexp2(u0), e1 = fexp2(u1);                                   \
        e0 = (b8 & (1u << (p2*2)))     ? e0 : 0.f;                              \
        e1 = (b8 & (1u << (p2*2 + 1))) ? e1 : 0.f;                              \
        asm("v_cvt_pk_bf16_f32 %0, %1, %2" : "=v"(pk[p2]) : "v"(e0), "v"(e1));  \
    }                                                                           \
    short8 af;                                                                  \
    ((uint*)&af)[0] = pk[0]; ((uint*)&af)[1] = pk[1];                           \
    ((uint*)&af)[2] = pk[2]; ((uint*)&af)[3] = pk[3];                           \
    accl = __builtin_amdgcn_mfma_f32_16x16x32_bf16(af, ones, accl, 0, 0, 0);    \
    _Pragma("unroll")                                                           \
    for (int c4 = 0; c4 < 4; c4++)                                              \
        acc[c4] = __builtin_amdgcn_mfma_f32_16x16x32_bf16(af, HC[c4], acc[c4], 0, 0, 0); }

    PRE_H(g*16, h0);
    uint4 abq = *(const uint4*)&abT[n16][g*16];
    for (int t4i = 0; t4i < 16; t4i += 4) {
        const int t4 = g*16 + t4i;
        const int tn = (t4i + 4 < 16) ? (t4 + 4) : g*16;
        uint4 abn = *(const uint4*)&abT[n16][tn];        // next group's bits (clamped)
        PRE_H(t4 + 1, h1);  SUBT(t4,     h0, abq.x);
        PRE_H(t4 + 2, h0);  SUBT(t4 + 1, h1, abq.y);
        PRE_H(t4 + 3, h1);  SUBT(t4 + 2, h0, abq.z);
        if (t4i + 4 < 16) PRE_H(t4 + 4, h0);
        SUBT(t4 + 3, h1, abq.w);
        abq = abn;
    }

    // ---- epilogue: merge m-groups, normalize, mean over heads ----
    __syncthreads();                      // all abT/edT reads done; reuse smem as merge buf
    float* mg = (float*)smem;             // [20][256]
    if (g == 1) {
        #pragma unroll
        for (int c4 = 0; c4 < 4; c4++)
            #pragma unroll
            for (int r = 0; r < 4; r++) mg[(c4*4 + r) * 256 + jg] = acc[c4][r];
        #pragma unroll
        for (int r = 0; r < 4; r++) mg[(16 + r) * 256 + jg] = accl[r];
    }
    __syncthreads();
    if (g == 0) {
        float rinv[4];
        #pragma unroll
        for (int r = 0; r < 4; r++)
            rinv[r] = 0.25f / (accl[r] + mg[(16 + r) * 256 + jg]);
        #pragma unroll
        for (int c4 = 0; c4 < 4; c4++)
            #pragma unroll
            for (int r = 0; r < 4; r++)
                o_lds[w][quad*4 + r][c4*16 + n16] =
                    (acc[c4][r] + mg[(c4*4 + r) * 256 + jg]) * rinv[r];
    }
    __syncthreads();

    {
        const int f = j & 63, r2 = (j >> 6) & 7;
        #pragma unroll
        for (int i = 0; i < 2; i++) {
            const int r = i*8 + r2;
            const float s = o_lds[0][r][f] + o_lds[1][r][f]
                          + o_lds[2][r][f] + o_lds[3][r][f];
            out[(rowb + r) * FO + f] = s;
        }
    }
#undef PRE_H
#undef SUBT
}

extern "C" void kernel_launch(void* const* d_in, const int* in_sizes, int n_in,
                              void* d_out, int out_size, void* d_ws, size_t ws_size,
                              hipStream_t stream) {
    const float* x   = (const float*)d_in[0];   // (8,1024,128) f32
    const int*   adj = (const int*)d_in[1];     // (8,1024,1024) i32
    const float* W   = (const float*)d_in[2];   // (128,256) f32
    const float* a   = (const float*)d_in[3];   // (4,128) f32
    float* out = (float*)d_out;                 // (8,1024,64) f32

    // ws: h_gB bf16 (4MB) | es (128KB) | ed (128KB) | adjbits (1MB)
    ushort* h_gB = (ushort*)d_ws;
    float*  es_g = (float*)(h_gB + (size_t)BN * COLS);
    float*  ed_g = es_g + (size_t)Hh * BN;
    uint*   abb  = (uint*)(ed_g + (size_t)Hh * BN);

    gat_proj<<<dim3(Bsz*Nsz/16),  dim3(256), 0, stream>>>(x, W, a, adj, h_gB, es_g, ed_g, abb);
    gat_attn<<<dim3(Bsz, Nsz/TN), dim3(512), 0, stream>>>(abb, h_gB, es_g, ed_g, out);
}

// Round 6
// 112.831 us; speedup vs baseline: 1.0514x; 1.0514x over previous
//
#include <hip/hip_runtime.h>
#include <math.h>

#define Bsz 8
#define Nsz 1024
#define FIN 128
#define Hh  4
#define FO  64
#define COLS 256   // Hh*FO
#define TN  16
#define TM  32
#define NT  (Nsz/TM)   // 32 m-tiles
#define BN  (Bsz*Nsz)
#define XSTR 136   // ushort stride per m-row of proj x-tile (128 data + 8 pad)
#define LOG2E  1.44269504088896340f
#define CSHIFT 17.3123404906675611f     // 12*log2(e): exp(s-12) == exp2(s*log2e - CSHIFT)
#define NEG08C (-0.8f * CSHIFT)         // leaky in t-domain: fma(0.2, t, -0.8C)

typedef __attribute__((ext_vector_type(8))) short short8;
typedef __attribute__((ext_vector_type(4))) float f32x4;

static __device__ inline ushort f2bf(float f) {           // RNE float->bf16
    uint u = __float_as_uint(f);
    u += 0x7FFFu + ((u >> 16) & 1u);
    return (ushort)(u >> 16);
}

static __device__ inline float fexp2(float x) {
#if __has_builtin(__builtin_amdgcn_exp2f)
    return __builtin_amdgcn_exp2f(x);
#else
    float r; asm("v_exp_f32 %0, %1" : "=v"(r) : "v"(x));
    return r;
#endif
}

// ---------------- prep: Wt[n][k] = bf16(W[k][n]) ----------------
// Tiny (8 blocks); removes the per-proj-block W transpose chain entirely.
__global__ __launch_bounds__(256) void gat_prep(const float* __restrict__ W,
                                                ushort* __restrict__ Wt)
{
    const int g = blockIdx.x * 256 + threadIdx.x;   // 0..2047
    const int n = g >> 3, kc = (g & 7) * 16;
    ushort u[16];
    #pragma unroll
    for (int i = 0; i < 16; i++) u[i] = f2bf(W[(kc + i) * COLS + n]);
    int4* dst = (int4*)(Wt + n * FIN + kc);
    dst[0] = ((int4*)u)[0];
    dst[1] = ((int4*)u)[1];
}

// ---------------- Kernel A: h = x@W via MFMA; es/ed (log2e-scaled, CSHIFT folded) ----
// grid 512, 256 thr, xs-only LDS (4.25 KB -> occupancy VGPR-bound, ~20 waves/CU).
// B fragments: 16 INDEPENDENT 16B loads from global Wt (L2-hot) -- one vmcnt
// round, no staging chain (round-5 lesson: the W-LDS transpose chain + 2
// blocks/CU left proj 96% stalled).
__global__ __launch_bounds__(256) void gat_proj(
    const float* __restrict__ x, const ushort* __restrict__ Wt,
    const float* __restrict__ a, ushort* __restrict__ h_gB,
    float* __restrict__ es_g, float* __restrict__ ed_g)
{
    __shared__ ushort xs[16 * XSTR];   // 4.25 KB
    const int j    = threadIdx.x;
    const int w    = j >> 6, lane = j & 63, quad = lane >> 4, n16 = lane & 15;
    const int b    = blockIdx.x >> 6, mt16 = blockIdx.x & 63;
    const long rowbase = (long)b * Nsz + mt16 * 16;

    // B fragments from global Wt (issued first; all independent)
    short8 bfr[4][4];
    #pragma unroll
    for (int kk = 0; kk < 4; kk++)
        #pragma unroll
        for (int c4 = 0; c4 < 4; c4++)
            bfr[kk][c4] = *(const short8*)(Wt + (w*64 + c4*16 + n16) * FIN + kk*32 + quad*8);

    // stage x tile (16x128) as bf16 into LDS
    {
        const int r = j >> 4, k0 = (j & 15) * 8;
        const float4* g4 = (const float4*)(x + (rowbase + r) * FIN + k0);
        float4 v0 = g4[0], v1 = g4[1];
        ushort u[8] = { f2bf(v0.x), f2bf(v0.y), f2bf(v0.z), f2bf(v0.w),
                        f2bf(v1.x), f2bf(v1.y), f2bf(v1.z), f2bf(v1.w) };
        *(int4*)(xs + r * XSTR + k0) = *(int4*)u;
    }
    __syncthreads();

    f32x4 acc[4];
    #pragma unroll
    for (int c4 = 0; c4 < 4; c4++)
        #pragma unroll
        for (int r = 0; r < 4; r++) acc[c4][r] = 0.f;

    #pragma unroll
    for (int kk = 0; kk < 4; kk++) {
        short8 af = *(const short8*)(xs + n16 * XSTR + kk*32 + quad*8);
        #pragma unroll
        for (int c4 = 0; c4 < 4; c4++)
            acc[c4] = __builtin_amdgcn_mfma_f32_16x16x32_bf16(af, bfr[kk][c4], acc[c4], 0, 0, 0);
    }

    // ---- h_gB store: [b][mt=row/32][c][k=row%32] bf16 ----
    const int mtile = mt16 >> 1;
    const int kbase = (mt16 & 1) * 16 + quad * 4;
    #pragma unroll
    for (int c4 = 0; c4 < 4; c4++) {
        uint2 pk;
        pk.x = (uint)f2bf(acc[c4][0]) | ((uint)f2bf(acc[c4][1]) << 16);
        pk.y = (uint)f2bf(acc[c4][2]) | ((uint)f2bf(acc[c4][3]) << 16);
        const int c = w*64 + c4*16 + n16;
        *(uint2*)(h_gB + (((long)(b*32 + mtile) * COLS + c) * 32 + kbase)) = pk;
    }

    // ---- es/ed from fp32 accumulators (log2e-scaled; CSHIFT folded into es) ----
    float aS[4], aD[4];
    #pragma unroll
    for (int c4 = 0; c4 < 4; c4++) {
        aS[c4] = a[w * (2*FO) + c4*16 + n16];
        aD[c4] = a[w * (2*FO) + FO + c4*16 + n16];
    }
    #pragma unroll
    for (int reg = 0; reg < 4; reg++) {
        float ps = 0.f, pd = 0.f;
        #pragma unroll
        for (int c4 = 0; c4 < 4; c4++) {
            ps = fmaf(acc[c4][reg], aS[c4], ps);
            pd = fmaf(acc[c4][reg], aD[c4], pd);
        }
        #pragma unroll
        for (int off = 1; off < 16; off <<= 1) {
            ps += __shfl_xor(ps, off, 64);
            pd += __shfl_xor(pd, off, 64);
        }
        if (n16 == 0) {
            const long row = rowbase + quad*4 + reg;
            es_g[(long)w * BN + row] = ps * LOG2E - CSHIFT;
            ed_g[(long)w * BN + row] = pd * LOG2E;
        }
    }
}

// ---------------- Kernel B: barrier-free main loop, in-block m-split, self adj-pack ----
// (round-4 version verbatim -- the best-measured attn config.)
// grid (Bsz, Nsz/TN), 512 thr. Group g = j>>8 owns m-tiles [16g, 16g+16).
// Wave (g,w) = head w; lane (n16, quad) computes p for row n16, m in [8q, 8q+8)
// == MFMA A-fragment layout, so p stays in registers; main loop has NO barriers.
// adj packed in-block via __ballot (64 coalesced cols per wave-op) into abT.
// Denominator l = P x ones via one extra MFMA (D-row layout).
__global__ __launch_bounds__(512, 4) void gat_attn(
    const int* __restrict__ adj, const ushort* __restrict__ h_gB,
    const float* __restrict__ es_g, const float* __restrict__ ed_g,
    float* __restrict__ out)
{
    // phase1: edT [0,16K) + abT [16K,18.25K) ; phase2: merge [0,20K) + o_lds [20K,36.25K)
    __shared__ __align__(16) char smem[20*1024 + Hh * TN * 65 * 4];
    float (*edT)[Nsz]      = (float (*)[Nsz])smem;                   // [Hh][1024]
    uint  (*abT)[36]       = (uint (*)[36])(smem + 16*1024);         // [16][36]
    float (*o_lds)[TN][65] = (float (*)[TN][65])(smem + 20*1024);    // [Hh][16][65]

    const int j    = threadIdx.x;
    const int g    = j >> 8;                  // m-group
    const int jg   = j & 255;
    const int w    = jg >> 6, lane = jg & 63, quad = lane >> 4, n16 = lane & 15;
    const int b    = blockIdx.x, n0 = blockIdx.y * TN;   // linear%8==b -> XCD b owns batch b
    const long rowb = (long)b * Nsz + n0;

    // stage edT[w][g*512 .. g*512+512): each (g,w) wave stages the half it consumes
    {
        const float* src = ed_g + (long)w * BN + (long)b * Nsz + g*512 + lane*8;
        float* dst = &edT[w][g*512 + lane*8];
        *(float4*)dst       = *(const float4*)src;
        *(float4*)(dst + 4) = *(const float4*)(src + 4);
    }
    // ballot-pack adj: block reads its 16 rows (64KB, contiguous) -> 16x32 uints
    {
        const int* ap = adj + rowb * (long)Nsz;
        #pragma unroll 4
        for (int k = 0; k < 32; k++) {
            const int idx = k*512 + j;              // 0..16383
            const int v = ap[idx];
            const unsigned long long m = __ballot(v > 0);
            if (lane == 0) {
                const int row = idx >> 10, col0 = idx & 1023;   // col0 is 64-aligned
                *(uint2*)&abT[row][col0 >> 5] = make_uint2((uint)m, (uint)(m >> 32));
            }
        }
    }
    const float esC = es_g[(long)w * BN + rowb + n16];   // log2e-scaled, -CSHIFT folded
    __syncthreads();                                     // the ONLY pre-epilogue barrier

    f32x4 acc[4], accl;
    #pragma unroll
    for (int c4 = 0; c4 < 4; c4++)
        #pragma unroll
        for (int r = 0; r < 4; r++) acc[c4][r] = 0.f;
    #pragma unroll
    for (int r = 0; r < 4; r++) accl[r] = 0.f;

    short8 ones;
    #pragma unroll
    for (int i = 0; i < 8; i++) ones[i] = (short)0x3F80;    // bf16 1.0

    const ushort* hb = h_gB + (long)b * (Nsz * COLS);
    short8 h0[4], h1[4];

#define PRE_H(t, H) {                                                           \
    const ushort* hp = hb + (long)(t) * (COLS * TM);                            \
    _Pragma("unroll")                                                           \
    for (int c4 = 0; c4 < 4; c4++)                                              \
        H[c4] = *(const short8*)(hp + (w*64 + c4*16 + n16) * TM + quad*8); }

#define SUBT(t, HC, ABU) {                                                      \
    f32x4 ev0 = *(const f32x4*)&edT[w][(t)*32 + quad*8];                        \
    f32x4 ev1 = *(const f32x4*)&edT[w][(t)*32 + quad*8 + 4];                    \
    const uint b8 = ((ABU) >> (quad*8)) & 0xffu;                                \
    uint pk[4];                                                                 \
    _Pragma("unroll")                                                           \
    for (int p2 = 0; p2 < 4; p2++) {                                            \
        float t0 = esC + (p2 < 2 ? ev0[p2*2]     : ev1[(p2-2)*2]);              \
        float t1 = esC + (p2 < 2 ? ev0[p2*2 + 1] : ev1[(p2-2)*2 + 1]);          \
        float u0 = fmaxf(t0, fmaf(0.2f, t0, NEG08C));                           \
        float u1 = fmaxf(t1, fmaf(0.2f, t1, NEG08C));                           \
        float e0 = fexp2(u0), e1 = fexp2(u1);                                   \
        e0 = (b8 & (1u << (p2*2)))     ? e0 : 0.f;                              \
        e1 = (b8 & (1u << (p2*2 + 1))) ? e1 : 0.f;                              \
        asm("v_cvt_pk_bf16_f32 %0, %1, %2" : "=v"(pk[p2]) : "v"(e0), "v"(e1));  \
    }                                                                           \
    short8 af;                                                                  \
    ((uint*)&af)[0] = pk[0]; ((uint*)&af)[1] = pk[1];                           \
    ((uint*)&af)[2] = pk[2]; ((uint*)&af)[3] = pk[3];                           \
    accl = __builtin_amdgcn_mfma_f32_16x16x32_bf16(af, ones, accl, 0, 0, 0);    \
    _Pragma("unroll")                                                           \
    for (int c4 = 0; c4 < 4; c4++)                                              \
        acc[c4] = __builtin_amdgcn_mfma_f32_16x16x32_bf16(af, HC[c4], acc[c4], 0, 0, 0); }

    PRE_H(g*16, h0);
    uint4 abq = *(const uint4*)&abT[n16][g*16];
    for (int t4i = 0; t4i < 16; t4i += 4) {
        const int t4 = g*16 + t4i;
        const int tn = (t4i + 4 < 16) ? (t4 + 4) : g*16;
        uint4 abn = *(const uint4*)&abT[n16][tn];        // next group's bits (clamped)
        PRE_H(t4 + 1, h1);  SUBT(t4,     h0, abq.x);
        PRE_H(t4 + 2, h0);  SUBT(t4 + 1, h1, abq.y);
        PRE_H(t4 + 3, h1);  SUBT(t4 + 2, h0, abq.z);
        if (t4i + 4 < 16) PRE_H(t4 + 4, h0);
        SUBT(t4 + 3, h1, abq.w);
        abq = abn;
    }

    // ---- epilogue: merge m-groups, normalize, mean over heads ----
    __syncthreads();                      // all abT/edT reads done; reuse smem as merge buf
    float* mg = (float*)smem;             // [20][256]
    if (g == 1) {
        #pragma unroll
        for (int c4 = 0; c4 < 4; c4++)
            #pragma unroll
            for (int r = 0; r < 4; r++) mg[(c4*4 + r) * 256 + jg] = acc[c4][r];
        #pragma unroll
        for (int r = 0; r < 4; r++) mg[(16 + r) * 256 + jg] = accl[r];
    }
    __syncthreads();
    if (g == 0) {
        float rinv[4];
        #pragma unroll
        for (int r = 0; r < 4; r++)
            rinv[r] = 0.25f / (accl[r] + mg[(16 + r) * 256 + jg]);
        #pragma unroll
        for (int c4 = 0; c4 < 4; c4++)
            #pragma unroll
            for (int r = 0; r < 4; r++)
                o_lds[w][quad*4 + r][c4*16 + n16] =
                    (acc[c4][r] + mg[(c4*4 + r) * 256 + jg]) * rinv[r];
    }
    __syncthreads();

    {
        const int f = j & 63, r2 = (j >> 6) & 7;
        #pragma unroll
        for (int i = 0; i < 2; i++) {
            const int r = i*8 + r2;
            const float s = o_lds[0][r][f] + o_lds[1][r][f]
                          + o_lds[2][r][f] + o_lds[3][r][f];
            out[(rowb + r) * FO + f] = s;
        }
    }
#undef PRE_H
#undef SUBT
}

extern "C" void kernel_launch(void* const* d_in, const int* in_sizes, int n_in,
                              void* d_out, int out_size, void* d_ws, size_t ws_size,
                              hipStream_t stream) {
    const float* x   = (const float*)d_in[0];   // (8,1024,128) f32
    const int*   adj = (const int*)d_in[1];     // (8,1024,1024) i32
    const float* W   = (const float*)d_in[2];   // (128,256) f32
    const float* a   = (const float*)d_in[3];   // (4,128) f32
    float* out = (float*)d_out;                 // (8,1024,64) f32

    // ws: Wt bf16 (64KB) | h_gB bf16 (4MB) | es (128KB) | ed (128KB)
    ushort* Wt   = (ushort*)d_ws;
    ushort* h_gB = Wt + (size_t)COLS * FIN;
    float*  es_g = (float*)(h_gB + (size_t)BN * COLS);
    float*  ed_g = es_g + (size_t)Hh * BN;

    gat_prep<<<dim3(8),           dim3(256), 0, stream>>>(W, Wt);
    gat_proj<<<dim3(Bsz*Nsz/16),  dim3(256), 0, stream>>>(x, Wt, a, h_gB, es_g, ed_g);
    gat_attn<<<dim3(Bsz, Nsz/TN), dim3(512), 0, stream>>>(adj, h_gB, es_g, ed_g, out);
}

// Round 8
// 112.498 us; speedup vs baseline: 1.0545x; 1.0030x over previous
//
#include <hip/hip_runtime.h>
#include <math.h>

#define Bsz 8
#define Nsz 1024
#define FIN 128
#define Hh  4
#define FO  64
#define COLS 256   // Hh*FO
#define TN  16
#define TM  32
#define NT  (Nsz/TM)   // 32 m-tiles
#define BN  (Bsz*Nsz)
#define XSTR 136   // ushort stride (128 data + 8 pad)
#define LOG2E  1.44269504088896340f
#define CSHIFT 17.3123404906675611f     // 12*log2(e): exp(s-12) == exp2(s*log2e - CSHIFT)
#define NEG08C (-0.8f * CSHIFT)         // leaky in t-domain: fma(0.2, t, -0.8C)

typedef __attribute__((ext_vector_type(8))) short short8;
typedef __attribute__((ext_vector_type(4))) float f32x4;

static __device__ inline ushort f2bf(float f) {           // RNE float->bf16
    uint u = __float_as_uint(f);
    u += 0x7FFFu + ((u >> 16) & 1u);
    return (ushort)(u >> 16);
}

static __device__ inline float fexp2(float x) {
#if __has_builtin(__builtin_amdgcn_exp2f)
    return __builtin_amdgcn_exp2f(x);
#else
    float r; asm("v_exp_f32 %0, %1" : "=v"(r) : "v"(x));
    return r;
#endif
}

// ---------------- Kernel A: h = x@W via MFMA; W converted in-block (R4 verbatim) ----
__global__ __launch_bounds__(256) void gat_proj(
    const float* __restrict__ x, const float* __restrict__ W,
    const float* __restrict__ a, ushort* __restrict__ h_gB,
    float* __restrict__ es_g, float* __restrict__ ed_g)
{
    __shared__ ushort xs[16 * XSTR];       // 4.25 KB
    __shared__ ushort wLDS[COLS * XSTR];   // 68 KB
    const int j    = threadIdx.x;
    const int w    = j >> 6, lane = j & 63, quad = lane >> 4, n16 = lane & 15;
    const int b    = blockIdx.x >> 6, mt16 = blockIdx.x & 63;
    const long rowbase = (long)b * Nsz + mt16 * 16;

    // stage x tile (16x128) as bf16 into LDS (HBM loads issued first)
    {
        const int r = j >> 4, k0 = (j & 15) * 8;
        const float4* g4 = (const float4*)(x + (rowbase + r) * FIN + k0);
        float4 v0 = g4[0], v1 = g4[1];
        ushort u[8] = { f2bf(v0.x), f2bf(v0.y), f2bf(v0.z), f2bf(v0.w),
                        f2bf(v1.x), f2bf(v1.y), f2bf(v1.z), f2bf(v1.w) };
        *(int4*)(xs + r * XSTR + k0) = *(int4*)u;
    }

    // stage W column j: wLDS[j][k] = bf16(W[k][j]) (coalesced across lanes)
    #pragma unroll
    for (int i8 = 0; i8 < 16; i8++) {
        float wv[8];
        #pragma unroll
        for (int ii = 0; ii < 8; ii++) wv[ii] = W[(i8*8 + ii) * COLS + j];
        uint pk4[4];
        #pragma unroll
        for (int i2 = 0; i2 < 4; i2++)
            asm("v_cvt_pk_bf16_f32 %0, %1, %2" : "=v"(pk4[i2]) : "v"(wv[2*i2]), "v"(wv[2*i2+1]));
        *(int4*)(wLDS + j * XSTR + i8*8) = *(int4*)pk4;
    }
    __syncthreads();

    // B fragments from wLDS (2-way bank aliasing on reads -> free)
    short8 bfr[4][4];
    #pragma unroll
    for (int kk = 0; kk < 4; kk++)
        #pragma unroll
        for (int c4 = 0; c4 < 4; c4++)
            bfr[kk][c4] = *(const short8*)(wLDS + (w*64 + c4*16 + n16) * XSTR + kk*32 + quad*8);

    f32x4 acc[4];
    #pragma unroll
    for (int c4 = 0; c4 < 4; c4++)
        #pragma unroll
        for (int r = 0; r < 4; r++) acc[c4][r] = 0.f;

    #pragma unroll
    for (int kk = 0; kk < 4; kk++) {
        short8 af = *(const short8*)(xs + n16 * XSTR + kk*32 + quad*8);
        #pragma unroll
        for (int c4 = 0; c4 < 4; c4++)
            acc[c4] = __builtin_amdgcn_mfma_f32_16x16x32_bf16(af, bfr[kk][c4], acc[c4], 0, 0, 0);
    }

    // ---- h_gB store: [b][mt=row/32][c][k=row%32] bf16 ----
    const int mtile = mt16 >> 1;
    const int kbase = (mt16 & 1) * 16 + quad * 4;
    #pragma unroll
    for (int c4 = 0; c4 < 4; c4++) {
        uint2 pk;
        pk.x = (uint)f2bf(acc[c4][0]) | ((uint)f2bf(acc[c4][1]) << 16);
        pk.y = (uint)f2bf(acc[c4][2]) | ((uint)f2bf(acc[c4][3]) << 16);
        const int c = w*64 + c4*16 + n16;
        *(uint2*)(h_gB + (((long)(b*32 + mtile) * COLS + c) * 32 + kbase)) = pk;
    }

    // ---- es/ed from fp32 accumulators (log2e-scaled; CSHIFT folded into es) ----
    float aS[4], aD[4];
    #pragma unroll
    for (int c4 = 0; c4 < 4; c4++) {
        aS[c4] = a[w * (2*FO) + c4*16 + n16];
        aD[c4] = a[w * (2*FO) + FO + c4*16 + n16];
    }
    #pragma unroll
    for (int reg = 0; reg < 4; reg++) {
        float ps = 0.f, pd = 0.f;
        #pragma unroll
        for (int c4 = 0; c4 < 4; c4++) {
            ps = fmaf(acc[c4][reg], aS[c4], ps);
            pd = fmaf(acc[c4][reg], aD[c4], pd);
        }
        #pragma unroll
        for (int off = 1; off < 16; off <<= 1) {
            ps += __shfl_xor(ps, off, 64);
            pd += __shfl_xor(pd, off, 64);
        }
        if (n16 == 0) {
            const long row = rowbase + quad*4 + reg;
            es_g[(long)w * BN + row] = ps * LOG2E - CSHIFT;
            ed_g[(long)w * BN + row] = pd * LOG2E;
        }
    }
}

// ---------------- Kernel B: R4 attn + 2-deep h-prefetch (4-buffer rotation),
// early first-tile issue, ballot unroll 8. Numerics identical to R4. ----
__global__ __launch_bounds__(512, 4) void gat_attn(
    const int* __restrict__ adj, const ushort* __restrict__ h_gB,
    const float* __restrict__ es_g, const float* __restrict__ ed_g,
    float* __restrict__ out)
{
    // phase1: edT [0,16K) + abT [16K,18.25K) ; phase2: merge [0,20K) + o_lds [20K,36.25K)
    __shared__ __align__(16) char smem[20*1024 + Hh * TN * 65 * 4];
    float (*edT)[Nsz]      = (float (*)[Nsz])smem;                   // [Hh][1024]
    uint  (*abT)[36]       = (uint (*)[36])(smem + 16*1024);         // [16][36]
    float (*o_lds)[TN][65] = (float (*)[TN][65])(smem + 20*1024);    // [Hh][16][65]

    const int j    = threadIdx.x;
    const int g    = j >> 8;                  // m-group
    const int jg   = j & 255;
    const int w    = jg >> 6, lane = jg & 63, quad = lane >> 4, n16 = lane & 15;
    const int b    = blockIdx.x, n0 = blockIdx.y * TN;   // linear%8==b -> XCD b owns batch b
    const long rowb = (long)b * Nsz + n0;

    // stage edT[w][g*512 .. g*512+512): each (g,w) wave stages the half it consumes
    {
        const float* src = ed_g + (long)w * BN + (long)b * Nsz + g*512 + lane*8;
        float* dst = &edT[w][g*512 + lane*8];
        *(float4*)dst       = *(const float4*)src;
        *(float4*)(dst + 4) = *(const float4*)(src + 4);
    }
    // ballot-pack adj: block reads its 16 rows (64KB, contiguous) -> 16x32 uints
    {
        const int* ap = adj + rowb * (long)Nsz;
        #pragma unroll 8
        for (int k = 0; k < 32; k++) {
            const int idx = k*512 + j;              // 0..16383
            const int v = ap[idx];
            const unsigned long long m = __ballot(v > 0);
            if (lane == 0) {
                const int row = idx >> 10, col0 = idx & 1023;   // col0 is 64-aligned
                *(uint2*)&abT[row][col0 >> 5] = make_uint2((uint)m, (uint)(m >> 32));
            }
        }
    }

    const ushort* hb = h_gB + (long)b * (Nsz * COLS);
    short8 h0[4], h1[4], h2[4], h3[4];

#define PRE_H(t, H) {                                                           \
    const ushort* hp = hb + (long)(t) * (COLS * TM);                            \
    _Pragma("unroll")                                                           \
    for (int c4 = 0; c4 < 4; c4++)                                              \
        H[c4] = *(const short8*)(hp + (w*64 + c4*16 + n16) * TM + quad*8); }

// clamped variant: ti is the in-group tile index (0..15); OOB clamps to 15 (harmless load)
#define PRE_HC(ti, H) { const int tc_ = ((ti) < 16) ? (ti) : 15; PRE_H(g*16 + tc_, H); }

    // early issue of the first two tiles: loads complete under the ballot phase /
    // barrier drain, giving the loop a warm 2-deep pipeline from iteration 0.
    PRE_H(g*16,     h0);
    PRE_H(g*16 + 1, h1);

    const float esC = es_g[(long)w * BN + rowb + n16];   // log2e-scaled, -CSHIFT folded
    __syncthreads();                                     // the ONLY pre-epilogue barrier

    f32x4 acc[4], accl;
    #pragma unroll
    for (int c4 = 0; c4 < 4; c4++)
        #pragma unroll
        for (int r = 0; r < 4; r++) acc[c4][r] = 0.f;
    #pragma unroll
    for (int r = 0; r < 4; r++) accl[r] = 0.f;

    short8 ones;
    #pragma unroll
    for (int i = 0; i < 8; i++) ones[i] = (short)0x3F80;    // bf16 1.0

#define SUBT(t, HC, ABU) {                                                      \
    f32x4 ev0 = *(const f32x4*)&edT[w][(t)*32 + quad*8];                        \
    f32x4 ev1 = *(const f32x4*)&edT[w][(t)*32 + quad*8 + 4];                    \
    const uint b8 = ((ABU) >> (quad*8)) & 0xffu;                                \
    uint pk[4];                                                                 \
    _Pragma("unroll")                                                           \
    for (int p2 = 0; p2 < 4; p2++) {                                            \
        float t0 = esC + (p2 < 2 ? ev0[p2*2]     : ev1[(p2-2)*2]);              \
        float t1 = esC + (p2 < 2 ? ev0[p2*2 + 1] : ev1[(p2-2)*2 + 1]);          \
        float u0 = fmaxf(t0, fmaf(0.2f, t0, NEG08C));                           \
        float u1 = fmaxf(t1, fmaf(0.2f, t1, NEG08C));                           \
        float e0 = fexp2(u0), e1 = fexp2(u1);                                   \
        e0 = (b8 & (1u << (p2*2)))     ? e0 : 0.f;                              \
        e1 = (b8 & (1u << (p2*2 + 1))) ? e1 : 0.f;                              \
        asm("v_cvt_pk_bf16_f32 %0, %1, %2" : "=v"(pk[p2]) : "v"(e0), "v"(e1));  \
    }                                                                           \
    short8 af;                                                                  \
    ((uint*)&af)[0] = pk[0]; ((uint*)&af)[1] = pk[1];                           \
    ((uint*)&af)[2] = pk[2]; ((uint*)&af)[3] = pk[3];                           \
    accl = __builtin_amdgcn_mfma_f32_16x16x32_bf16(af, ones, accl, 0, 0, 0);    \
    _Pragma("unroll")                                                           \
    for (int c4 = 0; c4 < 4; c4++)                                              \
        acc[c4] = __builtin_amdgcn_mfma_f32_16x16x32_bf16(af, HC[c4], acc[c4], 0, 0, 0); }

    // main loop: 2-deep prefetch, 4-buffer rotation (no register copies)
    uint4 abq = *(const uint4*)&abT[n16][g*16];
    for (int t4i = 0; t4i < 16; t4i += 4) {
        const int t4 = g*16 + t4i;
        const int tn = (t4i + 4 < 16) ? (t4 + 4) : g*16;
        uint4 abn = *(const uint4*)&abT[n16][tn];        // next group's bits (clamped)
        PRE_HC(t4i + 2, h2);  SUBT(t4,     h0, abq.x);
        PRE_HC(t4i + 3, h3);  SUBT(t4 + 1, h1, abq.y);
        PRE_HC(t4i + 4, h0);  SUBT(t4 + 2, h2, abq.z);
        PRE_HC(t4i + 5, h1);  SUBT(t4 + 3, h3, abq.w);
        abq = abn;
    }

    // ---- epilogue: merge m-groups, normalize, mean over heads ----
    __syncthreads();                      // all abT/edT reads done; reuse smem as merge buf
    float* mg = (float*)smem;             // [20][256]
    if (g == 1) {
        #pragma unroll
        for (int c4 = 0; c4 < 4; c4++)
            #pragma unroll
            for (int r = 0; r < 4; r++) mg[(c4*4 + r) * 256 + jg] = acc[c4][r];
        #pragma unroll
        for (int r = 0; r < 4; r++) mg[(16 + r) * 256 + jg] = accl[r];
    }
    __syncthreads();
    if (g == 0) {
        float rinv[4];
        #pragma unroll
        for (int r = 0; r < 4; r++)
            rinv[r] = 0.25f / (accl[r] + mg[(16 + r) * 256 + jg]);
        #pragma unroll
        for (int c4 = 0; c4 < 4; c4++)
            #pragma unroll
            for (int r = 0; r < 4; r++)
                o_lds[w][quad*4 + r][c4*16 + n16] =
                    (acc[c4][r] + mg[(c4*4 + r) * 256 + jg]) * rinv[r];
    }
    __syncthreads();

    {
        const int f = j & 63, r2 = (j >> 6) & 7;
        #pragma unroll
        for (int i = 0; i < 2; i++) {
            const int r = i*8 + r2;
            const float s = o_lds[0][r][f] + o_lds[1][r][f]
                          + o_lds[2][r][f] + o_lds[3][r][f];
            out[(rowb + r) * FO + f] = s;
        }
    }
#undef PRE_H
#undef PRE_HC
#undef SUBT
}

extern "C" void kernel_launch(void* const* d_in, const int* in_sizes, int n_in,
                              void* d_out, int out_size, void* d_ws, size_t ws_size,
                              hipStream_t stream) {
    const float* x   = (const float*)d_in[0];   // (8,1024,128) f32
    const int*   adj = (const int*)d_in[1];     // (8,1024,1024) i32
    const float* W   = (const float*)d_in[2];   // (128,256) f32
    const float* a   = (const float*)d_in[3];   // (4,128) f32
    float* out = (float*)d_out;                 // (8,1024,64) f32

    // ws: h_gB bf16 (4MB) | es (128KB) | ed (128KB)
    ushort* h_gB = (ushort*)d_ws;
    float*  es_g = (float*)(h_gB + (size_t)BN * COLS);
    float*  ed_g = es_g + (size_t)Hh * BN;

    gat_proj<<<dim3(Bsz*Nsz/16),  dim3(256), 0, stream>>>(x, W, a, h_gB, es_g, ed_g);
    gat_attn<<<dim3(Bsz, Nsz/TN), dim3(512), 0, stream>>>(adj, h_gB, es_g, ed_g, out);
}

// Round 9
// 110.147 us; speedup vs baseline: 1.0770x; 1.0213x over previous
//
#include <hip/hip_runtime.h>
#include <math.h>

#define Bsz 8
#define Nsz 1024
#define FIN 128
#define Hh  4
#define FO  64
#define COLS 256   // Hh*FO
#define TN  16
#define TM  32
#define NT  (Nsz/TM)   // 32 m-tiles
#define BN  (Bsz*Nsz)
#define XSTR 136   // ushort stride (128 data + 8 pad)
#define LOG2E  1.44269504088896340f
#define CSHIFT 17.3123404906675611f     // 12*log2(e): exp(s-12) == exp2(s*log2e - CSHIFT)
#define NEG08C (-0.8f * CSHIFT)         // leaky in t-domain: fma(0.2, t, -0.8C)

typedef __attribute__((ext_vector_type(8))) short short8;
typedef __attribute__((ext_vector_type(4))) float f32x4;

static __device__ inline ushort f2bf(float f) {           // RNE float->bf16
    uint u = __float_as_uint(f);
    u += 0x7FFFu + ((u >> 16) & 1u);
    return (ushort)(u >> 16);
}

static __device__ inline float fexp2(float x) {
#if __has_builtin(__builtin_amdgcn_exp2f)
    return __builtin_amdgcn_exp2f(x);
#else
    float r; asm("v_exp_f32 %0, %1" : "=v"(r) : "v"(x));
    return r;
#endif
}

// ---------------- Kernel A: h = x@W via MFMA; W converted in-block ----------------
// grid 512 = (b, 16-row tile), 256 thr. Wave w = head w (cols w*64..w*64+63).
// W staged per-block into wLDS as bf16 (coalesced dword loads, cvt_pk).
__global__ __launch_bounds__(256) void gat_proj(
    const float* __restrict__ x, const float* __restrict__ W,
    const float* __restrict__ a, ushort* __restrict__ h_gB,
    float* __restrict__ es_g, float* __restrict__ ed_g)
{
    __shared__ ushort xs[16 * XSTR];       // 4.25 KB
    __shared__ ushort wLDS[COLS * XSTR];   // 68 KB
    const int j    = threadIdx.x;
    const int w    = j >> 6, lane = j & 63, quad = lane >> 4, n16 = lane & 15;
    const int b    = blockIdx.x >> 6, mt16 = blockIdx.x & 63;
    const long rowbase = (long)b * Nsz + mt16 * 16;

    // stage x tile (16x128) as bf16 into LDS (HBM loads issued first)
    {
        const int r = j >> 4, k0 = (j & 15) * 8;
        const float4* g4 = (const float4*)(x + (rowbase + r) * FIN + k0);
        float4 v0 = g4[0], v1 = g4[1];
        ushort u[8] = { f2bf(v0.x), f2bf(v0.y), f2bf(v0.z), f2bf(v0.w),
                        f2bf(v1.x), f2bf(v1.y), f2bf(v1.z), f2bf(v1.w) };
        *(int4*)(xs + r * XSTR + k0) = *(int4*)u;
    }

    // stage W column j: wLDS[j][k] = bf16(W[k][j]) (coalesced across lanes)
    #pragma unroll
    for (int i8 = 0; i8 < 16; i8++) {
        float wv[8];
        #pragma unroll
        for (int ii = 0; ii < 8; ii++) wv[ii] = W[(i8*8 + ii) * COLS + j];
        uint pk4[4];
        #pragma unroll
        for (int i2 = 0; i2 < 4; i2++)
            asm("v_cvt_pk_bf16_f32 %0, %1, %2" : "=v"(pk4[i2]) : "v"(wv[2*i2]), "v"(wv[2*i2+1]));
        *(int4*)(wLDS + j * XSTR + i8*8) = *(int4*)pk4;
    }
    __syncthreads();

    // B fragments from wLDS (2-way bank aliasing on reads -> free)
    short8 bfr[4][4];
    #pragma unroll
    for (int kk = 0; kk < 4; kk++)
        #pragma unroll
        for (int c4 = 0; c4 < 4; c4++)
            bfr[kk][c4] = *(const short8*)(wLDS + (w*64 + c4*16 + n16) * XSTR + kk*32 + quad*8);

    f32x4 acc[4];
    #pragma unroll
    for (int c4 = 0; c4 < 4; c4++)
        #pragma unroll
        for (int r = 0; r < 4; r++) acc[c4][r] = 0.f;

    #pragma unroll
    for (int kk = 0; kk < 4; kk++) {
        short8 af = *(const short8*)(xs + n16 * XSTR + kk*32 + quad*8);
        #pragma unroll
        for (int c4 = 0; c4 < 4; c4++)
            acc[c4] = __builtin_amdgcn_mfma_f32_16x16x32_bf16(af, bfr[kk][c4], acc[c4], 0, 0, 0);
    }

    // ---- h_gB store: [b][mt=row/32][c][k=row%32] bf16 ----
    const int mtile = mt16 >> 1;
    const int kbase = (mt16 & 1) * 16 + quad * 4;
    #pragma unroll
    for (int c4 = 0; c4 < 4; c4++) {
        uint2 pk;
        pk.x = (uint)f2bf(acc[c4][0]) | ((uint)f2bf(acc[c4][1]) << 16);
        pk.y = (uint)f2bf(acc[c4][2]) | ((uint)f2bf(acc[c4][3]) << 16);
        const int c = w*64 + c4*16 + n16;
        *(uint2*)(h_gB + (((long)(b*32 + mtile) * COLS + c) * 32 + kbase)) = pk;
    }

    // ---- es/ed from fp32 accumulators (log2e-scaled; CSHIFT folded into es) ----
    float aS[4], aD[4];
    #pragma unroll
    for (int c4 = 0; c4 < 4; c4++) {
        aS[c4] = a[w * (2*FO) + c4*16 + n16];
        aD[c4] = a[w * (2*FO) + FO + c4*16 + n16];
    }
    #pragma unroll
    for (int reg = 0; reg < 4; reg++) {
        float ps = 0.f, pd = 0.f;
        #pragma unroll
        for (int c4 = 0; c4 < 4; c4++) {
            ps = fmaf(acc[c4][reg], aS[c4], ps);
            pd = fmaf(acc[c4][reg], aD[c4], pd);
        }
        #pragma unroll
        for (int off = 1; off < 16; off <<= 1) {
            ps += __shfl_xor(ps, off, 64);
            pd += __shfl_xor(pd, off, 64);
        }
        if (n16 == 0) {
            const long row = rowbase + quad*4 + reg;
            es_g[(long)w * BN + row] = ps * LOG2E - CSHIFT;
            ed_g[(long)w * BN + row] = pd * LOG2E;
        }
    }
}

// ---------------- Kernel B: barrier-free main loop, in-block m-split, self adj-pack ----
// grid (Bsz, Nsz/TN), 512 thr. Group g = j>>8 owns m-tiles [16g, 16g+16).
// Wave (g,w) = head w; lane (n16, quad) computes p for row n16, m in [8q, 8q+8)
// == MFMA A-fragment layout, so p stays in registers; main loop has NO barriers.
// adj packed in-block via __ballot (64 coalesced cols per wave-op) into abT.
// Denominator l = P x ones via one extra MFMA (D-row layout).
__global__ __launch_bounds__(512, 4) void gat_attn(
    const int* __restrict__ adj, const ushort* __restrict__ h_gB,
    const float* __restrict__ es_g, const float* __restrict__ ed_g,
    float* __restrict__ out)
{
    // phase1: edT [0,16K) + abT [16K,18.25K) ; phase2: merge [0,20K) + o_lds [20K,36.25K)
    __shared__ __align__(16) char smem[20*1024 + Hh * TN * 65 * 4];
    float (*edT)[Nsz]      = (float (*)[Nsz])smem;                   // [Hh][1024]
    uint  (*abT)[36]       = (uint (*)[36])(smem + 16*1024);         // [16][36]
    float (*o_lds)[TN][65] = (float (*)[TN][65])(smem + 20*1024);    // [Hh][16][65]

    const int j    = threadIdx.x;
    const int g    = j >> 8;                  // m-group
    const int jg   = j & 255;
    const int w    = jg >> 6, lane = jg & 63, quad = lane >> 4, n16 = lane & 15;
    const int b    = blockIdx.x, n0 = blockIdx.y * TN;   // linear%8==b -> XCD b owns batch b
    const long rowb = (long)b * Nsz + n0;

    // stage edT[w][g*512 .. g*512+512): each (g,w) wave stages the half it consumes
    {
        const float* src = ed_g + (long)w * BN + (long)b * Nsz + g*512 + lane*8;
        float* dst = &edT[w][g*512 + lane*8];
        *(float4*)dst       = *(const float4*)src;
        *(float4*)(dst + 4) = *(const float4*)(src + 4);
    }
    // ballot-pack adj: block reads its 16 rows (64KB, contiguous) -> 16x32 uints
    {
        const int* ap = adj + rowb * (long)Nsz;
        #pragma unroll 4
        for (int k = 0; k < 32; k++) {
            const int idx = k*512 + j;              // 0..16383
            const int v = ap[idx];
            const unsigned long long m = __ballot(v > 0);
            if (lane == 0) {
                const int row = idx >> 10, col0 = idx & 1023;   // col0 is 64-aligned
                *(uint2*)&abT[row][col0 >> 5] = make_uint2((uint)m, (uint)(m >> 32));
            }
        }
    }
    const float esC = es_g[(long)w * BN + rowb + n16];   // log2e-scaled, -CSHIFT folded
    __syncthreads();                                     // the ONLY pre-epilogue barrier

    f32x4 acc[4], accl;
    #pragma unroll
    for (int c4 = 0; c4 < 4; c4++)
        #pragma unroll
        for (int r = 0; r < 4; r++) acc[c4][r] = 0.f;
    #pragma unroll
    for (int r = 0; r < 4; r++) accl[r] = 0.f;

    short8 ones;
    #pragma unroll
    for (int i = 0; i < 8; i++) ones[i] = (short)0x3F80;    // bf16 1.0

    const ushort* hb = h_gB + (long)b * (Nsz * COLS);
    short8 h0[4], h1[4];

#define PRE_H(t, H) {                                                           \
    const ushort* hp = hb + (long)(t) * (COLS * TM);                            \
    _Pragma("unroll")                                                           \
    for (int c4 = 0; c4 < 4; c4++)                                              \
        H[c4] = *(const short8*)(hp + (w*64 + c4*16 + n16) * TM + quad*8); }

#define SUBT(t, HC, ABU) {                                                      \
    f32x4 ev0 = *(const f32x4*)&edT[w][(t)*32 + quad*8];                        \
    f32x4 ev1 = *(const f32x4*)&edT[w][(t)*32 + quad*8 + 4];                    \
    const uint b8 = ((ABU) >> (quad*8)) & 0xffu;                                \
    uint pk[4];                                                                 \
    _Pragma("unroll")                                                           \
    for (int p2 = 0; p2 < 4; p2++) {                                            \
        float t0 = esC + (p2 < 2 ? ev0[p2*2]     : ev1[(p2-2)*2]);              \
        float t1 = esC + (p2 < 2 ? ev0[p2*2 + 1] : ev1[(p2-2)*2 + 1]);          \
        float u0 = fmaxf(t0, fmaf(0.2f, t0, NEG08C));                           \
        float u1 = fmaxf(t1, fmaf(0.2f, t1, NEG08C));                           \
        float e0 = fexp2(u0), e1 = fexp2(u1);                                   \
        e0 = (b8 & (1u << (p2*2)))     ? e0 : 0.f;                              \
        e1 = (b8 & (1u << (p2*2 + 1))) ? e1 : 0.f;                              \
        asm("v_cvt_pk_bf16_f32 %0, %1, %2" : "=v"(pk[p2]) : "v"(e0), "v"(e1));  \
    }                                                                           \
    short8 af;                                                                  \
    ((uint*)&af)[0] = pk[0]; ((uint*)&af)[1] = pk[1];                           \
    ((uint*)&af)[2] = pk[2]; ((uint*)&af)[3] = pk[3];                           \
    accl = __builtin_amdgcn_mfma_f32_16x16x32_bf16(af, ones, accl, 0, 0, 0);    \
    _Pragma("unroll")                                                           \
    for (int c4 = 0; c4 < 4; c4++)                                              \
        acc[c4] = __builtin_amdgcn_mfma_f32_16x16x32_bf16(af, HC[c4], acc[c4], 0, 0, 0); }

    PRE_H(g*16, h0);
    uint4 abq = *(const uint4*)&abT[n16][g*16];
    for (int t4i = 0; t4i < 16; t4i += 4) {
        const int t4 = g*16 + t4i;
        const int tn = (t4i + 4 < 16) ? (t4 + 4) : g*16;
        uint4 abn = *(const uint4*)&abT[n16][tn];        // next group's bits (clamped)
        PRE_H(t4 + 1, h1);  SUBT(t4,     h0, abq.x);
        PRE_H(t4 + 2, h0);  SUBT(t4 + 1, h1, abq.y);
        PRE_H(t4 + 3, h1);  SUBT(t4 + 2, h0, abq.z);
        if (t4i + 4 < 16) PRE_H(t4 + 4, h0);
        SUBT(t4 + 3, h1, abq.w);
        abq = abn;
    }

    // ---- epilogue: merge m-groups, normalize, mean over heads ----
    __syncthreads();                      // all abT/edT reads done; reuse smem as merge buf
    float* mg = (float*)smem;             // [20][256]
    if (g == 1) {
        #pragma unroll
        for (int c4 = 0; c4 < 4; c4++)
            #pragma unroll
            for (int r = 0; r < 4; r++) mg[(c4*4 + r) * 256 + jg] = acc[c4][r];
        #pragma unroll
        for (int r = 0; r < 4; r++) mg[(16 + r) * 256 + jg] = accl[r];
    }
    __syncthreads();
    if (g == 0) {
        float rinv[4];
        #pragma unroll
        for (int r = 0; r < 4; r++)
            rinv[r] = 0.25f / (accl[r] + mg[(16 + r) * 256 + jg]);
        #pragma unroll
        for (int c4 = 0; c4 < 4; c4++)
            #pragma unroll
            for (int r = 0; r < 4; r++)
                o_lds[w][quad*4 + r][c4*16 + n16] =
                    (acc[c4][r] + mg[(c4*4 + r) * 256 + jg]) * rinv[r];
    }
    __syncthreads();

    {
        const int f = j & 63, r2 = (j >> 6) & 7;
        #pragma unroll
        for (int i = 0; i < 2; i++) {
            const int r = i*8 + r2;
            const float s = o_lds[0][r][f] + o_lds[1][r][f]
                          + o_lds[2][r][f] + o_lds[3][r][f];
            out[(rowb + r) * FO + f] = s;
        }
    }
#undef PRE_H
#undef SUBT
}

extern "C" void kernel_launch(void* const* d_in, const int* in_sizes, int n_in,
                              void* d_out, int out_size, void* d_ws, size_t ws_size,
                              hipStream_t stream) {
    const float* x   = (const float*)d_in[0];   // (8,1024,128) f32
    const int*   adj = (const int*)d_in[1];     // (8,1024,1024) i32
    const float* W   = (const float*)d_in[2];   // (128,256) f32
    const float* a   = (const float*)d_in[3];   // (4,128) f32
    float* out = (float*)d_out;                 // (8,1024,64) f32

    // ws: h_gB bf16 (4MB) | es (128KB) | ed (128KB)
    ushort* h_gB = (ushort*)d_ws;
    float*  es_g = (float*)(h_gB + (size_t)BN * COLS);
    float*  ed_g = es_g + (size_t)Hh * BN;

    gat_proj<<<dim3(Bsz*Nsz/16),  dim3(256), 0, stream>>>(x, W, a, h_gB, es_g, ed_g);
    gat_attn<<<dim3(Bsz, Nsz/TN), dim3(512), 0, stream>>>(adj, h_gB, es_g, ed_g, out);
}